// Round 1
// baseline (234.386 us; speedup 1.0000x reference)
//
#include <hip/hip_runtime.h>
#include <float.h>

#define NROWS 65536
#define DDIM  512

// ws layout (floats):
//   [0, 4096)    s8[8][512]  split accumulators for s = X^T k
//   [4096, 4608) t[512]      t = value_w^T s
//   [4608]       Menc (uint) order-encoded max of x
//   [4609]       sumexp
#define WS_S8   0
#define WS_T    4096
#define WS_M    4608
#define WS_SUM  4609
#define WS_HDR_BYTES ((4610) * 4)

__device__ __forceinline__ unsigned encf(float f) {
    unsigned u = __float_as_uint(f);
    return (u & 0x80000000u) ? ~u : (u | 0x80000000u);
}
__device__ __forceinline__ float decf(unsigned e) {
    unsigned u = (e & 0x80000000u) ? (e ^ 0x80000000u) : ~e;
    return __uint_as_float(u);
}

// Pass A: k[n] = row . key_w + key_b ; s += k[n] * row   (fused, one read of X)
__global__ __launch_bounds__(256) void kA(const float* __restrict__ in,
                                          const float* __restrict__ key_w,
                                          const float* __restrict__ key_b,
                                          float* __restrict__ s8) {
    const int lane = threadIdx.x & 63;
    const int wv   = threadIdx.x >> 6;
    const int gw   = blockIdx.x * 4 + wv;
    const int nw   = gridDim.x * 4;
    const float4* in4 = (const float4*)in;
    const float4* kw4 = (const float4*)key_w;
    const float4 kw0 = kw4[lane];
    const float4 kw1 = kw4[64 + lane];
    const float  kb  = key_b[0];
    float4 a0 = make_float4(0.f, 0.f, 0.f, 0.f);
    float4 a1 = make_float4(0.f, 0.f, 0.f, 0.f);

    for (int row = gw; row < NROWS; row += nw) {
        const float4* r = in4 + (size_t)row * (DDIM / 4);
        float4 v0 = r[lane];
        float4 v1 = r[64 + lane];
        float p = v0.x*kw0.x + v0.y*kw0.y + v0.z*kw0.z + v0.w*kw0.w
                + v1.x*kw1.x + v1.y*kw1.y + v1.z*kw1.z + v1.w*kw1.w;
        #pragma unroll
        for (int o = 32; o > 0; o >>= 1) p += __shfl_xor(p, o, 64);
        const float k = p + kb;
        a0.x += k*v0.x; a0.y += k*v0.y; a0.z += k*v0.z; a0.w += k*v0.w;
        a1.x += k*v1.x; a1.y += k*v1.y; a1.z += k*v1.z; a1.w += k*v1.w;
    }

    __shared__ float sb[4][512];
    sb[wv][4*lane+0]     = a0.x; sb[wv][4*lane+1]     = a0.y;
    sb[wv][4*lane+2]     = a0.z; sb[wv][4*lane+3]     = a0.w;
    sb[wv][256+4*lane+0] = a1.x; sb[wv][256+4*lane+1] = a1.y;
    sb[wv][256+4*lane+2] = a1.z; sb[wv][256+4*lane+3] = a1.w;
    __syncthreads();

    float* dst = s8 + (size_t)(blockIdx.x & 7) * 512;
    int d = threadIdx.x;
    atomicAdd(&dst[d], sb[0][d] + sb[1][d] + sb[2][d] + sb[3][d]);
    d += 256;
    atomicAdd(&dst[d], sb[0][d] + sb[1][d] + sb[2][d] + sb[3][d]);
}

// t[j] = sum_i value_w[i*512+j] * s[i]   (64 blocks x 8 rows of W each)
__global__ __launch_bounds__(512) void kB(const float* __restrict__ vw,
                                          const float* __restrict__ s8,
                                          float* __restrict__ t) {
    const int j = threadIdx.x;
    float acc = 0.f;
    #pragma unroll
    for (int ii = 0; ii < 8; ++ii) {
        const int i = blockIdx.x * 8 + ii;
        float si = 0.f;
        #pragma unroll
        for (int c = 0; c < 8; ++c) si += s8[c * 512 + i];
        acc += vw[(size_t)i * 512 + j] * si;
    }
    atomicAdd(&t[j], acc);
}

// Pass C: x[n] = row . t ; track global max (order-encoded atomicMax)
__global__ __launch_bounds__(256) void kC(const float* __restrict__ in,
                                          const float* __restrict__ t,
                                          float* __restrict__ x,
                                          unsigned* __restrict__ Menc) {
    const int lane = threadIdx.x & 63;
    const int wv   = threadIdx.x >> 6;
    const int gw   = blockIdx.x * 4 + wv;
    const int nw   = gridDim.x * 4;
    const float4* in4 = (const float4*)in;
    const float4* t4  = (const float4*)t;
    const float4 t0 = t4[lane];
    const float4 t1 = t4[64 + lane];
    float xmax = -FLT_MAX;

    for (int row = gw; row < NROWS; row += nw) {
        const float4* r = in4 + (size_t)row * (DDIM / 4);
        float4 v0 = r[lane];
        float4 v1 = r[64 + lane];
        float p = v0.x*t0.x + v0.y*t0.y + v0.z*t0.z + v0.w*t0.w
                + v1.x*t1.x + v1.y*t1.y + v1.z*t1.z + v1.w*t1.w;
        #pragma unroll
        for (int o = 32; o > 0; o >>= 1) p += __shfl_xor(p, o, 64);
        if (lane == 0) x[row] = p;
        xmax = fmaxf(xmax, p);
    }

    __shared__ float mb[4];
    if (lane == 0) mb[wv] = xmax;
    __syncthreads();
    if (threadIdx.x == 0) {
        float m = fmaxf(fmaxf(mb[0], mb[1]), fmaxf(mb[2], mb[3]));
        atomicMax(Menc, encf(m));
    }
}

// sumexp = sum_n exp(x[n] - M)
__global__ __launch_bounds__(256) void kD(const float* __restrict__ x,
                                          const unsigned* __restrict__ Menc,
                                          float* __restrict__ sum) {
    const float M = decf(*Menc);
    float acc = 0.f;
    for (int i = blockIdx.x * blockDim.x + threadIdx.x; i < NROWS;
         i += gridDim.x * blockDim.x)
        acc += expf(x[i] - M);
    #pragma unroll
    for (int o = 32; o > 0; o >>= 1) acc += __shfl_xor(acc, o, 64);
    __shared__ float sb[4];
    if ((threadIdx.x & 63) == 0) sb[threadIdx.x >> 6] = acc;
    __syncthreads();
    if (threadIdx.x == 0) atomicAdd(sum, sb[0] + sb[1] + sb[2] + sb[3]);
}

// out[n] = exp(x[n] - M) / sumexp  (in-place on d_out)
__global__ __launch_bounds__(256) void kE(float* __restrict__ x,
                                          const unsigned* __restrict__ Menc,
                                          const float* __restrict__ sum) {
    const float M = decf(*Menc);
    const float inv = 1.0f / *sum;
    for (int i = blockIdx.x * blockDim.x + threadIdx.x; i < NROWS;
         i += gridDim.x * blockDim.x)
        x[i] = expf(x[i] - M) * inv;
}

extern "C" void kernel_launch(void* const* d_in, const int* in_sizes, int n_in,
                              void* d_out, int out_size, void* d_ws, size_t ws_size,
                              hipStream_t stream) {
    const float* in    = (const float*)d_in[0];
    const float* key_w = (const float*)d_in[1];
    const float* key_b = (const float*)d_in[2];
    const float* vw    = (const float*)d_in[3];
    // d_in[4] (value_b) contributes only a uniform shift to the logits;
    // softmax is shift-invariant, so it is unused.

    float* ws  = (float*)d_ws;
    float* s8  = ws + WS_S8;
    float* t   = ws + WS_T;
    unsigned* Menc = (unsigned*)(ws + WS_M);
    float* sum = ws + WS_SUM;
    float* x   = (float*)d_out;   // logits computed in-place in d_out

    hipMemsetAsync(d_ws, 0, WS_HDR_BYTES, stream);
    kA<<<1024, 256, 0, stream>>>(in, key_w, key_b, s8);
    kB<<<64, 512, 0, stream>>>(vw, s8, t);
    kC<<<1024, 256, 0, stream>>>(in, t, x, Menc);
    kD<<<64, 256, 0, stream>>>(x, Menc, sum);
    kE<<<256, 256, 0, stream>>>(x, Menc, sum);
}